// Round 4
// baseline (2402.897 us; speedup 1.0000x reference)
//
#include <hip/hip_runtime.h>
#include <math.h>

#define SEQ 4096
#define B   128
#define H   128
#define TPB 512
#define BH  (B * H)

typedef float v2f __attribute__((ext_vector_type(2)));
typedef float v4f __attribute__((ext_vector_type(4)));

// DPP lane-permute move; all source lanes valid/active for the controls used.
template <int CTRL>
__device__ __forceinline__ float dpp_movf(float v) {
    int i = __builtin_bit_cast(int, v);
    int r = __builtin_amdgcn_update_dpp(0, i, CTRL, 0xF, 0xF, false);
    return __builtin_bit_cast(float, r);
}
#define DPP_XOR1 0xB1   // quad_perm [1,0,3,2]  : lane ^= 1
#define DPP_XOR2 0x4E   // quad_perm [2,3,0,1]  : lane ^= 2
#define DPP_ROR8 0x128  // row rotate 8 == lane ^= 8 within the 16-lane row
#define DPP_ROR4 0x124  // row rotate 4: writer lanes (ks<4) pair with a lane
                        // in the complementary quad-pair, row bits preserved
                        // (verified direction-immune)

// One persistent block per (layer, batch) chain: 256 blocks = 256 CUs,
// 8 waves = 2 per SIMD so co-resident waves hide each other's stalls.
// Thread (jg = tid>>4, ks = tid&15): 4 output rows [4jg,4jg+4) over the
// 8-wide K-slice [8ks, 8ks+8). Weight rows stored lane-permuted so the
// 5-op DPP reduce-scatter needs no selects. x comes straight from global
// (per-thread slice, 4-deep register ping-pong); only h lives in LDS
// (1 KB ping-pong, exactly one barrier per step).
__global__ __launch_bounds__(TPB, 2) void rnn_persist(
    const float* __restrict__ seq,    // (SEQ, B, H)
    const float* __restrict__ init,   // (2, 1, H)
    const float* __restrict__ Win0, const float* __restrict__ Wh0,
    const float* __restrict__ Win1, const float* __restrict__ Wh1,
    float* __restrict__ out)          // states (SEQ,B,H) then finals (2B, H)
{
    __shared__ float h_lds[2][H];

    const int tid = threadIdx.x;
    const int bid = blockIdx.x;
    const int l   = bid >> 7;
    const int b   = bid & (B - 1);
    const int ks  = tid & 15;
    const int jg  = tid >> 4;              // 0..31
    const int o1  = (ks >> 1) & 1, o0 = ks & 1;

    const float* Win = l ? Win1 : Win0;
    const float* Wh  = l ? Wh1  : Wh0;

    // Weights in registers; position i (bits b1,c) holds output row
    // jg*4 + 2*(b1^o1) + (c^o0) over K-slice [8ks, 8ks+8).
    v2f win[4][4], wh[4][4];
#pragma unroll
    for (int i = 0; i < 4; ++i) {
        const int b1 = (i >> 1) & 1, c = i & 1;
        const int jr = jg * 4 + 2 * (b1 ^ o1) + (c ^ o0);
        const float* wi = Win + jr * H + ks * 8;
        const float* wp = Wh  + jr * H + ks * 8;
#pragma unroll
        for (int q = 0; q < 4; ++q) {
            win[i][q] = *(const v2f*)(wi + 2 * q);
            wh [i][q] = *(const v2f*)(wp + 2 * q);
        }
    }

    if (tid < H) h_lds[0][tid] = init[l * H + tid];

    // Per-thread x slice, prefetched 4 steps deep in named ping-pong regs
    // (rule #20: all indexing static; 4-deep covers ~900-cyc HBM latency).
    const float* xbase = seq + (size_t)b * H + 8 * ks;
    v4f xA0 = *(const v4f*)(xbase);                 // x[0]
    v4f xA1 = *(const v4f*)(xbase + 4);
    v4f xB0 = *(const v4f*)(xbase + (size_t)BH);    // x[1]
    v4f xB1 = *(const v4f*)(xbase + (size_t)BH + 4);
    v4f xC0 = *(const v4f*)(xbase + 2 * (size_t)BH);// x[2]
    v4f xC1 = *(const v4f*)(xbase + 2 * (size_t)BH + 4);
    v4f xD0 = *(const v4f*)(xbase + 3 * (size_t)BH);// x[3]
    v4f xD1 = *(const v4f*)(xbase + 3 * (size_t)BH + 4);

    float* out_states = out + (size_t)b * H;
    const bool l1 = (l == 1);
    const bool wr = (ks < 4);
    const int  jw = jg * 4 + ks;               // this lane's row (when wr)

    __syncthreads();                           // h_lds[0] visible

#define STEP(CUR, NXT, X0, X1, T)                                              \
    do {                                                                       \
        v4f xa = X0, xb = X1;                                                  \
        if ((T) + 4 < SEQ) {  /* issue prefetch of x[T+4] into own buffer */   \
            X0 = *(const v4f*)(xbase + (size_t)((T) + 4) * BH);                \
            X1 = *(const v4f*)(xbase + (size_t)((T) + 4) * BH + 4);            \
        }                                                                      \
        v4f ha = *(const v4f*)&h_lds[CUR][8 * ks];                             \
        v4f hb = *(const v4f*)&h_lds[CUR][8 * ks + 4];                         \
        v2f xp0 = {xa.x, xa.y}, xp1 = {xa.z, xa.w};                            \
        v2f xp2 = {xb.x, xb.y}, xp3 = {xb.z, xb.w};                            \
        v2f hp0 = {ha.x, ha.y}, hp1 = {ha.z, ha.w};                            \
        v2f hp2 = {hb.x, hb.y}, hp3 = {hb.z, hb.w};                            \
        float p[4];                                                            \
        _Pragma("unroll")                                                      \
        for (int i = 0; i < 4; ++i) {                                          \
            v2f acc = xp0 * win[i][0];                                         \
            acc += xp1 * win[i][1];                                            \
            acc += xp2 * win[i][2];                                            \
            acc += xp3 * win[i][3];                                            \
            acc += hp0 * wh[i][0];                                             \
            acc += hp1 * wh[i][1];                                             \
            acc += hp2 * wh[i][2];                                             \
            acc += hp3 * wh[i][3];                                             \
            p[i] = acc.x + acc.y;                                              \
        }                                                                      \
        /* reduce-scatter over the 16 ks-lanes (weights pre-permuted) */       \
        float q0 = p[0] + dpp_movf<DPP_XOR1>(p[1]);                            \
        float q1 = p[2] + dpp_movf<DPP_XOR1>(p[3]);                            \
        float r  = q0 + dpp_movf<DPP_XOR2>(q1);                                \
        float s  = r  + dpp_movf<DPP_ROR8>(r);                                 \
        float S  = s  + dpp_movf<DPP_ROR4>(s); /* full sum on lanes ks<4 */    \
        float g  = 0.5f * S * (1.0f + erff(S * 0.70710678118654752f));         \
        if (wr) {                                                              \
            h_lds[NXT][jw] = g;                                                \
            if (l1) out_states[(size_t)(T) * BH + jw] = g;                     \
        }                                                                      \
        __syncthreads();                                                       \
    } while (0)

    for (int t = 0; t < SEQ; t += 4) {
        STEP(0, 1, xA0, xA1, t);       // uses x[t],   refills A with x[t+4]
        STEP(1, 0, xB0, xB1, t + 1);   // uses x[t+1], refills B
        STEP(0, 1, xC0, xC1, t + 2);   // uses x[t+2], refills C
        STEP(1, 0, xD0, xD1, t + 3);   // uses x[t+3], refills D
    }
#undef STEP

    // finals: concat(layer0 h, layer1 h) after the states. SEQ%2==0 -> buf 0.
    if (tid < H)
        out[(size_t)SEQ * BH + ((size_t)l * B + b) * H + tid] = h_lds[0][tid];
}

extern "C" void kernel_launch(void* const* d_in, const int* in_sizes, int n_in,
                              void* d_out, int out_size, void* d_ws, size_t ws_size,
                              hipStream_t stream) {
    const float* seq  = (const float*)d_in[0];
    const float* init = (const float*)d_in[1];
    const float* Win0 = (const float*)d_in[2];
    const float* Wh0  = (const float*)d_in[3];
    const float* Win1 = (const float*)d_in[4];
    const float* Wh1  = (const float*)d_in[5];
    float* out = (float*)d_out;

    rnn_persist<<<2 * B, TPB, 0, stream>>>(seq, init, Win0, Wh0, Win1, Wh1, out);
}

// Round 6
// 1991.858 us; speedup vs baseline: 1.2064x; 1.2064x over previous
//
#include <hip/hip_runtime.h>
#include <math.h>

#define SEQ 4096
#define B   128
#define H   128
#define TPB 512
#define BH  (B * H)

typedef float v2f __attribute__((ext_vector_type(2)));
typedef float v4f __attribute__((ext_vector_type(4)));

// DPP lane-permute move; all source lanes valid/active for the controls used.
template <int CTRL>
__device__ __forceinline__ float dpp_movf(float v) {
    int i = __builtin_bit_cast(int, v);
    int r = __builtin_amdgcn_update_dpp(0, i, CTRL, 0xF, 0xF, false);
    return __builtin_bit_cast(float, r);
}
#define DPP_XOR1 0xB1   // quad_perm [1,0,3,2]  : lane ^= 1
#define DPP_XOR2 0x4E   // quad_perm [2,3,0,1]  : lane ^= 2
#define DPP_ROR8 0x128  // row rotate 8 == lane ^= 8 within the 16-lane row
#define DPP_ROR4 0x124  // row rotate 4: writer lanes (ks<4) receive the
                        // complementary bit2-half, row bits 0-1 preserved
                        // (verified direction-immune)

// Workgroup barrier WITHOUT the vmcnt drain __syncthreads carries.
// LDS dataflow is fully covered by lgkmcnt(0) (waits own ds_write AND this
// step's ds_reads); "memory" clobber pins all ds ops on their side. Global
// x-prefetch loads legally stay in flight across it — that drain was the
// hidden ~600 cyc/step in round 3's numbers.
#define BLOCK_SYNC_NO_VMDRAIN() \
    asm volatile("s_waitcnt lgkmcnt(0)\n\ts_barrier" ::: "memory")

// Branch-free exact-form GELU: 0.5*v*(1+erf(v/sqrt(2))) with A&S 7.1.26 erf
// (|err| <= 1.5e-7 — below the summation-order noise already in this chain).
// NO libm call: a non-inlined __ocml_erf_f32 call in the hot loop was the
// round-3 killer (ABI forced weights out of VGPRs; VGPR=72).
__device__ __forceinline__ float gelu_erf(float v) {
    float z  = v * 0.70710678118654752f;
    float az = __builtin_fabsf(z);
    float t  = __builtin_amdgcn_rcpf(fmaf(0.3275911f, az, 1.0f));
    float p  = fmaf(1.061405429f, t, -1.453152027f);
    p = fmaf(p, t, 1.421413741f);
    p = fmaf(p, t, -0.284496736f);
    p = fmaf(p, t, 0.254829592f);
    p = p * t;
    float e  = __builtin_amdgcn_exp2f(az * az * -1.4426950408889634f);
    float er = fmaf(-p, e, 1.0f);            // erf(|z|)
    er = __builtin_copysignf(er, z);
    float hv = 0.5f * v;
    return fmaf(hv, er, hv);
}

// LDS swizzle for h: float index j -> j + ((j>>5)&3)*4. Spreads the
// stride-32B ds_read_b128 pattern so every bank is exactly 2-way (free per
// m136), killing the 6.7e7 4-way conflicts measured in round 3. Offsets are
// loop-invariant. Piecewise-linear within 32-float chunks, so 4/8-float
// vector accesses at 8*ks stay contiguous.
__device__ __forceinline__ int hswz(int j) { return j + (((j >> 5) & 3) << 2); }
#define HPAD 140   // max swizzled index 139

// One persistent block per (layer, batch) chain: 256 blocks = 256 CUs,
// 8 waves = 2 per SIMD. Thread (jg = tid>>4, ks = tid&15): 4 output rows
// [4jg,4jg+4) over K-slice [8ks,8ks+8), weight rows lane-permuted so the
// 5-op DPP reduce-scatter needs no selects. x straight from global
// (4-deep register ping-pong, survives barriers); h in swizzled LDS,
// exactly one drain-free barrier per step.
__global__ __launch_bounds__(TPB, 2) void rnn_persist(
    const float* __restrict__ seq,    // (SEQ, B, H)
    const float* __restrict__ init,   // (2, 1, H)
    const float* __restrict__ Win0, const float* __restrict__ Wh0,
    const float* __restrict__ Win1, const float* __restrict__ Wh1,
    float* __restrict__ out)          // states (SEQ,B,H) then finals (2B, H)
{
    __shared__ float h_lds[2][HPAD];

    const int tid = threadIdx.x;
    const int bid = blockIdx.x;
    const int l   = bid >> 7;
    const int b   = bid & (B - 1);
    const int ks  = tid & 15;
    const int jg  = tid >> 4;              // 0..31
    const int o1  = (ks >> 1) & 1, o0 = ks & 1;

    const float* Win = l ? Win1 : Win0;
    const float* Wh  = l ? Wh1  : Wh0;

    // Weights in registers; position i (bits b1,c) holds output row
    // jg*4 + 2*(b1^o1) + (c^o0) over K-slice [8ks, 8ks+8).
    v2f win[4][4], wh[4][4];
#pragma unroll
    for (int i = 0; i < 4; ++i) {
        const int b1 = (i >> 1) & 1, c = i & 1;
        const int jr = jg * 4 + 2 * (b1 ^ o1) + (c ^ o0);
        const float* wi = Win + jr * H + ks * 8;
        const float* wp = Wh  + jr * H + ks * 8;
#pragma unroll
        for (int q = 0; q < 4; ++q) {
            win[i][q] = *(const v2f*)(wi + 2 * q);
            wh [i][q] = *(const v2f*)(wp + 2 * q);
        }
    }
    // Launder weights through empty asm: non-rematerializable asm results,
    // so regalloc keeps all 128 floats VGPR-resident instead of re-fetching
    // them every step (round-3 failure mode, VGPR=72).
#pragma unroll
    for (int i = 0; i < 4; ++i) {
        asm volatile("" : "+v"(win[i][0]), "+v"(win[i][1]),
                          "+v"(win[i][2]), "+v"(win[i][3]),
                          "+v"(wh[i][0]),  "+v"(wh[i][1]),
                          "+v"(wh[i][2]),  "+v"(wh[i][3]));
    }

    if (tid < H) h_lds[0][hswz(tid)] = init[l * H + tid];

    // Per-thread x slice: uniform scalar base + constant lane offset;
    // 4-deep named ping-pong regs (covers ~900-cyc HBM miss latency now
    // that barriers no longer drain vmcnt).
    const float* xs  = seq + (size_t)b * H;   // uniform per block
    const int    xo  = 8 * ks;                // per-lane, constant
    v4f xA0 = *(const v4f*)(xs + xo);
    v4f xA1 = *(const v4f*)(xs + xo + 4);
    v4f xB0 = *(const v4f*)(xs + (size_t)BH + xo);
    v4f xB1 = *(const v4f*)(xs + (size_t)BH + xo + 4);
    v4f xC0 = *(const v4f*)(xs + 2 * (size_t)BH + xo);
    v4f xC1 = *(const v4f*)(xs + 2 * (size_t)BH + xo + 4);
    v4f xD0 = *(const v4f*)(xs + 3 * (size_t)BH + xo);
    v4f xD1 = *(const v4f*)(xs + 3 * (size_t)BH + xo + 4);

    float* out_states = out + (size_t)b * H;  // uniform per block
    const bool l1 = (l == 1);
    const bool wr = (ks < 4);
    const int  jw = jg * 4 + ks;              // lane's row (when wr)
    const int  jws = hswz(jw);                // swizzled LDS index, invariant

    __syncthreads();                          // init visible (one-time drain ok)

#define STEP(CUR, NXT, X0, X1, T)                                              \
    do {                                                                       \
        v4f xa = X0, xb = X1;                                                  \
        if ((T) + 4 < SEQ) {  /* refill own buffer with x[T+4] */              \
            X0 = *(const v4f*)(xs + (size_t)((T) + 4) * BH + xo);              \
            X1 = *(const v4f*)(xs + (size_t)((T) + 4) * BH + xo + 4);          \
        }                                                                      \
        v4f ha = *(const v4f*)&h_lds[CUR][hswz(8 * ks)];                       \
        v4f hb = *(const v4f*)&h_lds[CUR][hswz(8 * ks + 4)];                   \
        v2f xp0 = {xa.x, xa.y}, xp1 = {xa.z, xa.w};                            \
        v2f xp2 = {xb.x, xb.y}, xp3 = {xb.z, xb.w};                            \
        v2f hp0 = {ha.x, ha.y}, hp1 = {ha.z, ha.w};                            \
        v2f hp2 = {hb.x, hb.y}, hp3 = {hb.z, hb.w};                            \
        float p[4];                                                            \
        _Pragma("unroll")                                                      \
        for (int i = 0; i < 4; ++i) {                                          \
            v2f acc = xp0 * win[i][0];                                         \
            acc += xp1 * win[i][1];                                            \
            acc += xp2 * win[i][2];                                            \
            acc += xp3 * win[i][3];                                            \
            acc += hp0 * wh[i][0];                                             \
            acc += hp1 * wh[i][1];                                             \
            acc += hp2 * wh[i][2];                                             \
            acc += hp3 * wh[i][3];                                             \
            p[i] = acc.x + acc.y;                                              \
        }                                                                      \
        /* reduce-scatter over the 16 ks-lanes (weights pre-permuted) */       \
        float q0 = p[0] + dpp_movf<DPP_XOR1>(p[1]);                            \
        float q1 = p[2] + dpp_movf<DPP_XOR1>(p[3]);                            \
        float r  = q0 + dpp_movf<DPP_XOR2>(q1);                                \
        float s  = r  + dpp_movf<DPP_ROR8>(r);                                 \
        float S  = s  + dpp_movf<DPP_ROR4>(s); /* full sum on lanes ks<4 */    \
        float g  = gelu_erf(S);                                                \
        if (wr) {                                                              \
            h_lds[NXT][jws] = g;                                               \
            if (l1) out_states[(size_t)(T) * BH + jw] = g;                     \
        }                                                                      \
        BLOCK_SYNC_NO_VMDRAIN();                                               \
    } while (0)

    for (int t = 0; t < SEQ; t += 4) {
        STEP(0, 1, xA0, xA1, t);       // uses x[t],   refills A with x[t+4]
        STEP(1, 0, xB0, xB1, t + 1);   // uses x[t+1], refills B
        STEP(0, 1, xC0, xC1, t + 2);   // uses x[t+2], refills C
        STEP(1, 0, xD0, xD1, t + 3);   // uses x[t+3], refills D
    }
#undef STEP

    // finals: concat(layer0 h, layer1 h) after the states. SEQ%2==0 -> buf 0.
    if (tid < H)
        out[(size_t)SEQ * BH + ((size_t)l * B + b) * H + tid] =
            h_lds[0][hswz(tid)];
}

extern "C" void kernel_launch(void* const* d_in, const int* in_sizes, int n_in,
                              void* d_out, int out_size, void* d_ws, size_t ws_size,
                              hipStream_t stream) {
    const float* seq  = (const float*)d_in[0];
    const float* init = (const float*)d_in[1];
    const float* Win0 = (const float*)d_in[2];
    const float* Wh0  = (const float*)d_in[3];
    const float* Win1 = (const float*)d_in[4];
    const float* Wh1  = (const float*)d_in[5];
    float* out = (float*)d_out;

    rnn_persist<<<2 * B, TPB, 0, stream>>>(seq, init, Win0, Wh0, Win1, Wh1, out);
}

// Round 8
// 1978.622 us; speedup vs baseline: 1.2144x; 1.0067x over previous
//
#include <hip/hip_runtime.h>
#include <math.h>

#define SEQ 4096
#define B   128
#define H   128
#define TPB 512
#define BH  (B * H)

typedef float v2f __attribute__((ext_vector_type(2)));
typedef float v4f __attribute__((ext_vector_type(4)));

// DPP lane-permute move; all source lanes valid/active for the controls used.
template <int CTRL>
__device__ __forceinline__ float dpp_movf(float v) {
    int i = __builtin_bit_cast(int, v);
    int r = __builtin_amdgcn_update_dpp(0, i, CTRL, 0xF, 0xF, false);
    return __builtin_bit_cast(float, r);
}
#define DPP_XOR1 0xB1   // quad_perm [1,0,3,2]  : lane ^= 1
#define DPP_XOR2 0x4E   // quad_perm [2,3,0,1]  : lane ^= 2
#define DPP_ROR8 0x128  // row rotate 8 == lane ^= 8 within the 16-lane row
#define DPP_ROR4 0x124  // row rotate 4: writer lanes (ks<4) receive the
                        // complementary bit2-half, row bits 0-1 preserved
                        // (verified direction-immune)

// Workgroup barrier WITHOUT the vmcnt drain __syncthreads carries.
// LDS dataflow fully covered by lgkmcnt(0); "memory" clobber pins ds ops.
// Global x-prefetch loads stay in flight across it (round-5 win: −530 µs).
#define BLOCK_SYNC_NO_VMDRAIN() \
    asm volatile("s_waitcnt lgkmcnt(0)\n\ts_barrier" ::: "memory")

// Branch-free exact-form GELU: 0.5*v*(1+erf(v/sqrt(2))) with A&S 7.1.26 erf
// (|err| <= 1.5e-7, below this chain's existing rounding noise). No libm
// call (round-3 killer: non-inlined __ocml_erf_f32 wrecked regalloc).
__device__ __forceinline__ float gelu_erf(float v) {
    float z  = v * 0.70710678118654752f;
    float az = __builtin_fabsf(z);
    float t  = __builtin_amdgcn_rcpf(fmaf(0.3275911f, az, 1.0f));
    float p  = fmaf(1.061405429f, t, -1.453152027f);
    p = fmaf(p, t, 1.421413741f);
    p = fmaf(p, t, -0.284496736f);
    p = fmaf(p, t, 0.254829592f);
    p = p * t;
    float e  = __builtin_amdgcn_exp2f(az * az * -1.4426950408889634f);
    float er = fmaf(-p, e, 1.0f);            // erf(|z|)
    er = __builtin_copysignf(er, z);
    float hv = 0.5f * v;
    return fmaf(hv, er, hv);
}

// LDS swizzle for h: j -> j + ((j>>5)&3)*4. Stride-32B b128 pattern becomes
// exactly 2-way per bank (free per m136). Loop-invariant offsets;
// piecewise-linear within 32-float chunks so b128 reads stay contiguous.
__device__ __forceinline__ int hswz(int j) { return j + (((j >> 5) & 3) << 2); }
#define HPAD 140   // max swizzled index 139

// One persistent block per (layer, batch) chain: 256 blocks = 256 CUs,
// 8 waves = 2 per SIMD. Thread (jg = tid>>4, ks = tid&15): 4 output rows
// [4jg,4jg+4) over K-slice [8ks,8ks+8), weight rows lane-permuted so the
// 5-op DPP reduce-scatter needs no selects. x straight from global
// (4-deep register ping-pong, survives barriers); h in swizzled LDS,
// exactly one drain-free barrier per step.
//
// amdgpu_waves_per_eu(2,2): round-5 evidence (VGPR_Count=72 with 64 weight
// floats laundered live + ~85 extra VALU instr/step) shows the backend
// parked the weights in AGPRs chasing unreachable occupancy (grid is 1
// block/CU). Pinning the occupancy target to exactly 2 waves/EU gives
// regalloc the full 256-VGPR budget so the weights stay architected.
__global__ __launch_bounds__(TPB)
__attribute__((amdgpu_waves_per_eu(2, 2))) void rnn_persist(
    const float* __restrict__ seq,    // (SEQ, B, H)
    const float* __restrict__ init,   // (2, 1, H)
    const float* __restrict__ Win0, const float* __restrict__ Wh0,
    const float* __restrict__ Win1, const float* __restrict__ Wh1,
    float* __restrict__ out)          // states (SEQ,B,H) then finals (2B, H)
{
    __shared__ float h_lds[2][HPAD];

    const int tid = threadIdx.x;
    const int bid = blockIdx.x;
    const int l   = bid >> 7;
    const int b   = bid & (B - 1);
    const int ks  = tid & 15;
    const int jg  = tid >> 4;              // 0..31
    const int o1  = (ks >> 1) & 1, o0 = ks & 1;

    const float* Win = l ? Win1 : Win0;
    const float* Wh  = l ? Wh1  : Wh0;

    // Weights in registers; position i (bits b1,c) holds output row
    // jg*4 + 2*(b1^o1) + (c^o0) over K-slice [8ks, 8ks+8).
    v2f win[4][4], wh[4][4];
#pragma unroll
    for (int i = 0; i < 4; ++i) {
        const int b1 = (i >> 1) & 1, c = i & 1;
        const int jr = jg * 4 + 2 * (b1 ^ o1) + (c ^ o0);
        const float* wi = Win + jr * H + ks * 8;
        const float* wp = Wh  + jr * H + ks * 8;
#pragma unroll
        for (int q = 0; q < 4; ++q) {
            win[i][q] = *(const v2f*)(wi + 2 * q);
            wh [i][q] = *(const v2f*)(wp + 2 * q);
        }
    }
    // Launder weights through empty asm: non-rematerializable asm results,
    // guaranteed live across the loop (in VGPRs given the 256 budget).
#pragma unroll
    for (int i = 0; i < 4; ++i) {
        asm volatile("" : "+v"(win[i][0]), "+v"(win[i][1]),
                          "+v"(win[i][2]), "+v"(win[i][3]),
                          "+v"(wh[i][0]),  "+v"(wh[i][1]),
                          "+v"(wh[i][2]),  "+v"(wh[i][3]));
    }

    if (tid < H) h_lds[0][hswz(tid)] = init[l * H + tid];

    // Per-thread x slice: uniform scalar base + constant lane offset;
    // 4-deep named ping-pong regs (covers ~900-cyc HBM miss latency since
    // barriers no longer drain vmcnt).
    const float* xs  = seq + (size_t)b * H;   // uniform per block
    const int    xo  = 8 * ks;                // per-lane, constant
    v4f xA0 = *(const v4f*)(xs + xo);
    v4f xA1 = *(const v4f*)(xs + xo + 4);
    v4f xB0 = *(const v4f*)(xs + (size_t)BH + xo);
    v4f xB1 = *(const v4f*)(xs + (size_t)BH + xo + 4);
    v4f xC0 = *(const v4f*)(xs + 2 * (size_t)BH + xo);
    v4f xC1 = *(const v4f*)(xs + 2 * (size_t)BH + xo + 4);
    v4f xD0 = *(const v4f*)(xs + 3 * (size_t)BH + xo);
    v4f xD1 = *(const v4f*)(xs + 3 * (size_t)BH + xo + 4);

    float* out_states = out + (size_t)b * H;  // uniform per block
    const bool l1 = (l == 1);
    const bool wr = (ks < 4);
    const int  jw = jg * 4 + ks;              // lane's row (when wr)
    const int  jws = hswz(jw);                // swizzled LDS index, invariant

    __syncthreads();                          // init visible (one-time drain ok)

#define STEP(CUR, NXT, X0, X1, T)                                              \
    do {                                                                       \
        v4f xa = X0, xb = X1;                                                  \
        if ((T) + 4 < SEQ) {  /* refill own buffer with x[T+4] */              \
            X0 = *(const v4f*)(xs + (size_t)((T) + 4) * BH + xo);              \
            X1 = *(const v4f*)(xs + (size_t)((T) + 4) * BH + xo + 4);          \
        }                                                                      \
        v4f ha = *(const v4f*)&h_lds[CUR][hswz(8 * ks)];                       \
        v4f hb = *(const v4f*)&h_lds[CUR][hswz(8 * ks + 4)];                   \
        v2f xp0 = {xa.x, xa.y}, xp1 = {xa.z, xa.w};                            \
        v2f xp2 = {xb.x, xb.y}, xp3 = {xb.z, xb.w};                            \
        v2f hp0 = {ha.x, ha.y}, hp1 = {ha.z, ha.w};                            \
        v2f hp2 = {hb.x, hb.y}, hp3 = {hb.z, hb.w};                            \
        float p[4];                                                            \
        _Pragma("unroll")                                                      \
        for (int i = 0; i < 4; ++i) {                                          \
            v2f acc = xp0 * win[i][0];                                         \
            acc += xp1 * win[i][1];                                            \
            acc += xp2 * win[i][2];                                            \
            acc += xp3 * win[i][3];                                            \
            acc += hp0 * wh[i][0];                                             \
            acc += hp1 * wh[i][1];                                             \
            acc += hp2 * wh[i][2];                                             \
            acc += hp3 * wh[i][3];                                             \
            p[i] = acc.x + acc.y;                                              \
        }                                                                      \
        /* reduce-scatter over the 16 ks-lanes (weights pre-permuted) */       \
        float q0 = p[0] + dpp_movf<DPP_XOR1>(p[1]);                            \
        float q1 = p[2] + dpp_movf<DPP_XOR1>(p[3]);                            \
        float r  = q0 + dpp_movf<DPP_XOR2>(q1);                                \
        float s  = r  + dpp_movf<DPP_ROR8>(r);                                 \
        float S  = s  + dpp_movf<DPP_ROR4>(s); /* full sum on lanes ks<4 */    \
        float g  = gelu_erf(S);                                                \
        if (wr) {                                                              \
            h_lds[NXT][jws] = g;                                               \
            if (l1) out_states[(size_t)(T) * BH + jw] = g;                     \
        }                                                                      \
        BLOCK_SYNC_NO_VMDRAIN();                                               \
    } while (0)

    for (int t = 0; t < SEQ; t += 4) {
        STEP(0, 1, xA0, xA1, t);       // uses x[t],   refills A with x[t+4]
        STEP(1, 0, xB0, xB1, t + 1);   // uses x[t+1], refills B
        STEP(0, 1, xC0, xC1, t + 2);   // uses x[t+2], refills C
        STEP(1, 0, xD0, xD1, t + 3);   // uses x[t+3], refills D
    }
#undef STEP

    // finals: concat(layer0 h, layer1 h) after the states. SEQ%2==0 -> buf 0.
    if (tid < H)
        out[(size_t)SEQ * BH + ((size_t)l * B + b) * H + tid] =
            h_lds[0][hswz(tid)];
}

extern "C" void kernel_launch(void* const* d_in, const int* in_sizes, int n_in,
                              void* d_out, int out_size, void* d_ws, size_t ws_size,
                              hipStream_t stream) {
    const float* seq  = (const float*)d_in[0];
    const float* init = (const float*)d_in[1];
    const float* Win0 = (const float*)d_in[2];
    const float* Wh0  = (const float*)d_in[3];
    const float* Win1 = (const float*)d_in[4];
    const float* Wh1  = (const float*)d_in[5];
    float* out = (float*)d_out;

    rnn_persist<<<2 * B, TPB, 0, stream>>>(seq, init, Win0, Wh0, Win1, Wh1, out);
}